// Round 2
// baseline (622.018 us; speedup 1.0000x reference)
//
#include <hip/hip_runtime.h>
#include <stdint.h>

#define NNODES 8192
#define KP1 4096
#define KP2 2048
#define FIN 16
#define FH 32
#define COUT 2
#define STRA 320   // max off-diag nnz/row stored; mean ~163, sigma ~12.6 -> 320 is >12 sigma
#define STRS 320

// Pass 1: stream the 256MB dense adjacency ONCE -> ELL col indices (off-diag),
// diagonal flag, degree -> dnorm = rsqrt(deg_hat + 1e-10).
__global__ __launch_bounds__(256) void build_ell(const float* __restrict__ A, int n, int stride,
        int* __restrict__ ell, int* __restrict__ rowcnt, int* __restrict__ diag, float* __restrict__ dnorm)
{
    __shared__ int cnt;
    __shared__ int dg;
    int row = blockIdx.x;
    if (threadIdx.x == 0) { cnt = 0; dg = 0; }
    __syncthreads();
    const float* arow = A + (size_t)row * n;
    int* erow = ell + (size_t)row * stride;
    for (int c = threadIdx.x; c < n; c += 256) {
        float v = arow[c];
        if (v != 0.0f) {
            if (c == row) {
                dg = 1;  // single writer: only the c==row thread
            } else {
                int p = atomicAdd(&cnt, 1);
                if (p < stride) erow[p] = c;
            }
        }
    }
    __syncthreads();
    if (threadIdx.x == 0) {
        int cf = cnt;
        rowcnt[row] = cf < stride ? cf : stride;
        diag[row] = dg;
        // deg_hat = offdiag_count + a_ii + 1 (self loop); all values are exactly 1.0
        dnorm[row] = rsqrtf((float)(cf + dg + 1) + 1e-10f);
    }
}

// Z = gather/mask(X) @ W   (tiny GEMMs; one thread per output element)
// j = gather ? gather[i] : i ; row treated as zero if j<0 or mask[i]<0
__global__ __launch_bounds__(256) void feat_gemm(const float* __restrict__ X, const int* __restrict__ gather,
        const int* __restrict__ mask, const float* __restrict__ W, float* __restrict__ Z,
        int n, int kdim, int fout)
{
    int t = blockIdx.x * 256 + threadIdx.x;
    int i = t / fout;
    int f = t - i * fout;
    if (i >= n) return;
    int j = i;
    if (gather) j = gather[i];
    int ok = (j >= 0);
    if (mask && mask[i] < 0) ok = 0;
    float acc = 0.0f;
    if (ok) {
        const float* xr = X + (size_t)j * kdim;
        for (int k = 0; k < kdim; ++k) acc += xr[k] * W[k * fout + f];
    }
    Z[(size_t)i * fout + f] = acc;
}

// SpMM (F=32) + relu, optional fused score = X_out @ svec.
// One wave per row: two 32-lane halves split the neighbor list, feature = lane&31.
// out[i] = relu( d_i * ( sum_{j in nbr} d_j * Z[j] + (a_ii+1)*d_i*Z[i] ) )
__global__ __launch_bounds__(256) void spmm_f32(const int* __restrict__ ell, const int* __restrict__ rowcnt,
        const int* __restrict__ diag, const float* __restrict__ dnorm, const float* __restrict__ Z,
        float* __restrict__ X, float* __restrict__ scores, const float* __restrict__ svec,
        int n, int stride)
{
    int wid = (blockIdx.x * 256 + threadIdx.x) >> 6;
    int lane = threadIdx.x & 63;
    if (wid >= n) return;
    int half = lane >> 5;
    int f = lane & 31;
    int cnt = rowcnt[wid];
    const int* erow = ell + (size_t)wid * stride;
    float acc = 0.0f;
    for (int it = half; it < cnt; it += 2) {
        int c = erow[it];
        acc += dnorm[c] * Z[c * 32 + f];
    }
    acc += __shfl_xor(acc, 32);
    if (half == 0) {
        float dr = dnorm[wid];
        float coef = (float)(diag[wid] + 1);
        acc += coef * dr * Z[wid * 32 + f];
        float o = fmaxf(dr * acc, 0.0f);
        X[wid * 32 + f] = o;
        if (scores) {
            float p = o * svec[f];
            p += __shfl_xor(p, 16);
            p += __shfl_xor(p, 8);
            p += __shfl_xor(p, 4);
            p += __shfl_xor(p, 2);
            p += __shfl_xor(p, 1);
            if (f == 0) scores[wid] = p;
        }
    }
}

// Final SpMM (F=2) + 2-way softmax
__global__ __launch_bounds__(256) void spmm_out(const int* __restrict__ ell, const int* __restrict__ rowcnt,
        const int* __restrict__ diag, const float* __restrict__ dnorm, const float* __restrict__ Z,
        float* __restrict__ out, int n, int stride)
{
    int wid = (blockIdx.x * 256 + threadIdx.x) >> 6;
    int lane = threadIdx.x & 63;
    if (wid >= n) return;
    int slot = lane >> 1;
    int f = lane & 1;
    int cnt = rowcnt[wid];
    const int* erow = ell + (size_t)wid * stride;
    float acc = 0.0f;
    for (int it = slot; it < cnt; it += 32) {
        int c = erow[it];
        acc += dnorm[c] * Z[c * 2 + f];
    }
    acc += __shfl_xor(acc, 2);
    acc += __shfl_xor(acc, 4);
    acc += __shfl_xor(acc, 8);
    acc += __shfl_xor(acc, 16);
    acc += __shfl_xor(acc, 32);
    if (lane < 2) {
        float dr = dnorm[wid];
        float coef = (float)(diag[wid] + 1);
        acc += coef * dr * Z[wid * 2 + f];
        float v = dr * acc;
        float w = __shfl_xor(v, 1);
        float m = fmaxf(v, w);
        float e = __expf(v - m);
        float eo = __expf(w - m);
        out[wid * 2 + f] = e / (e + eo);
    }
}

// Exact top-K selection replicating jax.lax.top_k SET semantics (value desc,
// lower-index-first ties). Single block, 256 threads. Radix-select the K-th
// key (4x8-bit passes), then tie-exact selection via packed (lt,eq) prefix.
// Outputs: rank[v] in [0,K) for selected (ascending index order), -1 else;
// idxlist[rank] = v (ascending).
__global__ __launch_bounds__(256) void topk_select(const float* __restrict__ scores, int n, int K,
        int* __restrict__ rank, int* __restrict__ idxlist)
{
    __shared__ unsigned int km_s[8192];
    __shared__ unsigned int part_s[256];
    __shared__ unsigned int hist[256];
    __shared__ unsigned int sh_pref;
    __shared__ unsigned int sh_rem;
    int tid = threadIdx.x;
    int per = n >> 8;       // 32 (N=8192) or 16 (N=4096)
    int base = tid * per;
    for (int e = 0; e < per; ++e) {
        int v = base + e;
        unsigned int u = __float_as_uint(scores[v]);
        unsigned int m;
        if (u & 0x80000000u) m = ~u; else m = u | 0x80000000u;  // monotone asc in float
        km_s[v] = ~m;                                           // asc in km == desc in score
    }
    if (tid == 0) { sh_pref = 0u; sh_rem = (unsigned int)K; }
    __syncthreads();
    for (int bp = 3; bp >= 0; --bp) {
        hist[tid] = 0u;
        __syncthreads();
        unsigned int maskhi = 0u;
        if (bp < 3) maskhi = 0xFFFFFFFFu << ((bp + 1) * 8);
        unsigned int pref = sh_pref;
        for (int e = 0; e < per; ++e) {
            unsigned int km = km_s[base + e];
            if ((km & maskhi) == pref) atomicAdd(&hist[(km >> (bp * 8)) & 255u], 1u);
        }
        __syncthreads();
        if (tid == 0) {
            unsigned int rem = sh_rem;
            int b = 0;
            while (b < 256) {
                unsigned int h = hist[b];
                if (h >= rem) break;
                rem -= h;
                ++b;
            }
            sh_pref = pref | ((unsigned int)b << (bp * 8));
            sh_rem = rem;
        }
        __syncthreads();
    }
    unsigned int T = sh_pref;       // K-th smallest km
    unsigned int need_eq = sh_rem;  // how many km==T to take (lowest node index first)
    // packed counts: high16 = #(km<T), low16 = #(km==T)
    unsigned int run = 0u;
    for (int e = 0; e < per; ++e) {
        unsigned int km = km_s[base + e];
        if (km < T) run += 0x10000u;
        else if (km == T) run += 1u;
    }
    part_s[tid] = run;
    __syncthreads();
    for (int offd = 1; offd < 256; offd <<= 1) {
        unsigned int add = 0u;
        if (tid >= offd) add = part_s[tid - offd];
        __syncthreads();
        part_s[tid] += add;
        __syncthreads();
    }
    unsigned int cur = part_s[tid] - run;   // exclusive prefix for this thread's chunk
    for (int e = 0; e < per; ++e) {
        int v = base + e;
        unsigned int km = km_s[v];
        unsigned int ltb = cur >> 16;
        unsigned int eqb = cur & 0xFFFFu;
        unsigned int eqs = eqb < need_eq ? eqb : need_eq;  // selected equals before v
        int sel = 0;
        if (km < T) { sel = 1; cur += 0x10000u; }
        else if (km == T) { if (eqb < need_eq) sel = 1; cur += 1u; }
        if (sel) {
            int r = (int)(ltb + eqs);       // rank = #selected with index < v
            rank[v] = r;
            idxlist[r] = v;
        } else {
            rank[v] = -1;
        }
    }
}

// Build subgraph ELL for A1p = a[idx1][:,idx1] by filtering the main ELL
// through rank1 (wave-compaction via ballot). One wave per subgraph row.
__global__ __launch_bounds__(256) void build_subell(const int* __restrict__ ellA, const int* __restrict__ rowcntA,
        const int* __restrict__ diagA, const int* __restrict__ idx1, const int* __restrict__ rank1,
        int* __restrict__ ellS, int* __restrict__ rowcntS, int* __restrict__ diagS, float* __restrict__ dnormS,
        int k1, int strideA, int strideS)
{
    int wid = (blockIdx.x * 256 + threadIdx.x) >> 6;
    int lane = threadIdx.x & 63;
    if (wid >= k1) return;
    int r = idx1[wid];
    int cnt = rowcntA[r];
    const int* erow = ellA + (size_t)r * strideA;
    int* srow = ellS + (size_t)wid * strideS;
    int outn = 0;
    for (int t0 = 0; t0 < cnt; t0 += 64) {
        int it = t0 + lane;
        int rk = -1;
        if (it < cnt) rk = rank1[erow[it]];
        unsigned long long b = __ballot(rk >= 0);
        int ofs = __popcll(b & ((1ull << lane) - 1ull));
        if (rk >= 0) srow[outn + ofs] = rk;
        outn += __popcll(b);
    }
    if (lane == 0) {
        int dg = diagA[r];              // A1p diagonal entry = a[r][r]
        rowcntS[wid] = outn;
        diagS[wid] = dg;
        dnormS[wid] = rsqrtf((float)(outn + dg + 1) + 1e-10f);
    }
}

#define CARVE(type, name, bytes) \
    type name = (type)wp; wp += (((size_t)(bytes)) + 255) & ~((size_t)255);

extern "C" void kernel_launch(void* const* d_in, const int* in_sizes, int n_in,
                              void* d_out, int out_size, void* d_ws, size_t ws_size,
                              hipStream_t stream)
{
    const float* x  = (const float*)d_in[0];
    const float* a  = (const float*)d_in[1];
    const float* W1 = (const float*)d_in[2];
    const float* W2 = (const float*)d_in[3];
    const float* W3 = (const float*)d_in[4];
    const float* W4 = (const float*)d_in[5];
    const float* s1 = (const float*)d_in[6];
    const float* s2 = (const float*)d_in[7];
    float* out = (float*)d_out;
    (void)in_sizes; (void)n_in; (void)out_size; (void)ws_size;

    char* wp = (char*)d_ws;
    CARVE(int*,   ellA,  (size_t)NNODES * STRA * sizeof(int));   // 10.5 MB
    CARVE(int*,   cntA,  NNODES * sizeof(int));
    CARVE(int*,   diagA, NNODES * sizeof(int));
    CARVE(float*, dnA,   NNODES * sizeof(float));
    CARVE(float*, Z1,    (size_t)NNODES * FH * sizeof(float));
    CARVE(float*, X1,    (size_t)NNODES * FH * sizeof(float));
    CARVE(float*, sc1,   NNODES * sizeof(float));
    CARVE(int*,   rank1, NNODES * sizeof(int));
    CARVE(int*,   idx1,  NNODES * sizeof(int));
    CARVE(int*,   ellS,  (size_t)KP1 * STRS * sizeof(int));      // 5.2 MB
    CARVE(int*,   cntS,  KP1 * sizeof(int));
    CARVE(int*,   diagS, KP1 * sizeof(int));
    CARVE(float*, dnS,   KP1 * sizeof(float));
    CARVE(float*, Z2,    (size_t)KP1 * FH * sizeof(float));
    CARVE(float*, X2,    (size_t)KP1 * FH * sizeof(float));
    CARVE(float*, sc2,   KP1 * sizeof(float));
    CARVE(int*,   rank2, KP1 * sizeof(int));
    CARVE(int*,   idx2,  KP1 * sizeof(int));
    CARVE(float*, Z3,    (size_t)KP1 * FH * sizeof(float));
    CARVE(float*, X3g,   (size_t)KP1 * FH * sizeof(float));
    CARVE(float*, Z4,    (size_t)NNODES * COUT * sizeof(float));

    // one full pass over a (256 MB) -> sparse structure + degrees
    build_ell<<<NNODES, 256, 0, stream>>>(a, NNODES, STRA, ellA, cntA, diagA, dnA);
    // GCN1: Z1 = x@W1 ; X1 = relu(Anorm@Z1) ; sc1 = X1@s1
    feat_gemm<<<(NNODES * FH) / 256, 256, 0, stream>>>(x, (const int*)0, (const int*)0, W1, Z1, NNODES, FIN, FH);
    spmm_f32<<<NNODES / 4, 256, 0, stream>>>(ellA, cntA, diagA, dnA, Z1, X1, sc1, s1, NNODES, STRA);
    // pool1 (exact top-k set, index-ascending order — permutation-equivalent)
    topk_select<<<1, 256, 0, stream>>>(sc1, NNODES, KP1, rank1, idx1);
    build_subell<<<KP1 / 4, 256, 0, stream>>>(ellA, cntA, diagA, idx1, rank1, ellS, cntS, diagS, dnS, KP1, STRA, STRS);
    // GCN2 on subgraph: Z2 = X1[idx1]@W2 ; X2 = relu(...) ; sc2 = X2@s2
    feat_gemm<<<(KP1 * FH) / 256, 256, 0, stream>>>(X1, idx1, (const int*)0, W2, Z2, KP1, FH, FH);
    spmm_f32<<<KP1 / 4, 256, 0, stream>>>(ellS, cntS, diagS, dnS, Z2, X2, sc2, s2, KP1, STRS);
    // pool2 + unpool2 collapse to a row mask (scatter back to the same slots)
    topk_select<<<1, 256, 0, stream>>>(sc2, KP1, KP2, rank2, idx2);
    // GCN3: Z3 = mask(X2)@W3 ; X3g = relu(...)
    feat_gemm<<<(KP1 * FH) / 256, 256, 0, stream>>>(X2, (const int*)0, rank2, W3, Z3, KP1, FH, FH);
    spmm_f32<<<KP1 / 4, 256, 0, stream>>>(ellS, cntS, diagS, dnS, Z3, X3g, (float*)0, (const float*)0, KP1, STRS);
    // unpool1 folded into gather: Z4[v] = (rank1[v]>=0 ? X3g[rank1[v]] : 0) @ W4
    feat_gemm<<<(NNODES * COUT) / 256, 256, 0, stream>>>(X3g, rank1, (const int*)0, W4, Z4, NNODES, FH, COUT);
    // GCN4 + softmax
    spmm_out<<<NNODES / 4, 256, 0, stream>>>(ellA, cntA, diagA, dnA, Z4, out, NNODES, STRA);
}

// Round 4
// 506.764 us; speedup vs baseline: 1.2274x; 1.2274x over previous
//
#include <hip/hip_runtime.h>
#include <stdint.h>

#define NNODES 8192
#define KP1 4096
#define KP2 2048
#define FIN 16
#define FH 32
#define COUT 2
#define STRA 320   // max off-diag nnz/row; mean ~163, sigma ~12.6 -> >12 sigma headroom
#define STRS 320

// Pass 1: stream the 256MB dense adjacency ONCE (float4) -> ELL col indices (off-diag),
// diagonal flag, degree -> dnorm = rsqrt(deg_hat + 1e-10).
__global__ __launch_bounds__(256) void build_ell(const float* __restrict__ A, int n, int stride,
        int* __restrict__ ell, int* __restrict__ rowcnt, int* __restrict__ diag, float* __restrict__ dnorm)
{
    __shared__ int cnt;
    __shared__ int dg;
    int row = blockIdx.x;
    if (threadIdx.x == 0) { cnt = 0; dg = 0; }
    __syncthreads();
    const float4* arow4 = (const float4*)(A + (size_t)row * n);
    int* erow = ell + (size_t)row * stride;
    int n4 = n >> 2;
    for (int c4 = threadIdx.x; c4 < n4; c4 += 256) {
        float4 v = arow4[c4];
        int cb = c4 << 2;
        if (v.x != 0.0f) {
            if (cb == row) dg = 1;
            else { int p = atomicAdd(&cnt, 1); if (p < stride) erow[p] = cb; }
        }
        if (v.y != 0.0f) {
            int c = cb + 1;
            if (c == row) dg = 1;
            else { int p = atomicAdd(&cnt, 1); if (p < stride) erow[p] = c; }
        }
        if (v.z != 0.0f) {
            int c = cb + 2;
            if (c == row) dg = 1;
            else { int p = atomicAdd(&cnt, 1); if (p < stride) erow[p] = c; }
        }
        if (v.w != 0.0f) {
            int c = cb + 3;
            if (c == row) dg = 1;
            else { int p = atomicAdd(&cnt, 1); if (p < stride) erow[p] = c; }
        }
    }
    __syncthreads();
    if (threadIdx.x == 0) {
        int cf = cnt;
        rowcnt[row] = cf < stride ? cf : stride;
        diag[row] = dg;
        // deg_hat = offdiag_count + a_ii + 1 (self loop); all values are exactly 1.0
        dnorm[row] = rsqrtf((float)(cf + dg + 1) + 1e-10f);
    }
}

// Z = gather/mask(X) @ W   (tiny GEMMs; one thread per output element)
// j = gather ? gather[i] : i ; row treated as zero if j<0 or mask[i]<0
__global__ __launch_bounds__(256) void feat_gemm(const float* __restrict__ X, const int* __restrict__ gather,
        const int* __restrict__ mask, const float* __restrict__ W, float* __restrict__ Z,
        int n, int kdim, int fout)
{
    int t = blockIdx.x * 256 + threadIdx.x;
    int i = t / fout;
    int f = t - i * fout;
    if (i >= n) return;
    int j = i;
    if (gather) j = gather[i];
    int ok = (j >= 0);
    if (mask && mask[i] < 0) ok = 0;
    float acc = 0.0f;
    if (ok) {
        const float* xr = X + (size_t)j * kdim;
        for (int k = 0; k < kdim; ++k) acc += xr[k] * W[k * fout + f];
    }
    Z[(size_t)i * fout + f] = acc;
}

// SpMM (F=32) + relu (+ fused score). One wave per row; 8 lanes per neighbor, float4 per lane.
// remap: neighbor id c -> row of Z (pooled graphs read full-space Z). maskp: skip c if maskp[c]<0.
__global__ __launch_bounds__(256) void spmm_f32(const int* __restrict__ ell, const int* __restrict__ rowcnt,
        const int* __restrict__ diag, const float* __restrict__ dnorm, const float* __restrict__ Z,
        const int* __restrict__ remap, const int* __restrict__ maskp,
        float* __restrict__ X, float* __restrict__ scores, const float* __restrict__ svec,
        int n, int stride)
{
    int wid = (blockIdx.x * 256 + threadIdx.x) >> 6;
    int lane = threadIdx.x & 63;
    if (wid >= n) return;
    int g = lane >> 3;   // neighbor sub-slot 0..7
    int q = lane & 7;    // feature quad 0..7
    int cnt = rowcnt[wid];
    const int* erow = ell + (size_t)wid * stride;
    float ax = 0.0f, ay = 0.0f, az = 0.0f, aw = 0.0f;
    for (int it = g; it < cnt; it += 8) {
        int c = erow[it];
        if (maskp && maskp[c] < 0) continue;
        int zc = c;
        if (remap) zc = remap[c];
        float dn = dnorm[c];
        const float4* zp = (const float4*)(Z + (size_t)zc * 32);
        float4 zv = zp[q];
        ax += dn * zv.x;
        ay += dn * zv.y;
        az += dn * zv.z;
        aw += dn * zv.w;
    }
    ax += __shfl_xor(ax, 8);
    ay += __shfl_xor(ay, 8);
    az += __shfl_xor(az, 8);
    aw += __shfl_xor(aw, 8);
    ax += __shfl_xor(ax, 16);
    ay += __shfl_xor(ay, 16);
    az += __shfl_xor(az, 16);
    aw += __shfl_xor(aw, 16);
    ax += __shfl_xor(ax, 32);
    ay += __shfl_xor(ay, 32);
    az += __shfl_xor(az, 32);
    aw += __shfl_xor(aw, 32);
    if (g == 0) {   // lanes 0..7 hold the full sum for feature quad q
        float dr = dnorm[wid];
        int selfok = 1;
        if (maskp && maskp[wid] < 0) selfok = 0;
        if (selfok) {
            int zc = wid;
            if (remap) zc = remap[wid];
            const float4* zp = (const float4*)(Z + (size_t)zc * 32);
            float4 zv = zp[q];
            float cf = (float)(diag[wid] + 1) * dr;
            ax += cf * zv.x;
            ay += cf * zv.y;
            az += cf * zv.z;
            aw += cf * zv.w;
        }
        float4 o;
        o.x = fmaxf(dr * ax, 0.0f);
        o.y = fmaxf(dr * ay, 0.0f);
        o.z = fmaxf(dr * az, 0.0f);
        o.w = fmaxf(dr * aw, 0.0f);
        float4* xp = (float4*)(X + (size_t)wid * 32);
        xp[q] = o;
        if (scores) {
            const float4* sp = (const float4*)svec;
            float4 sv = sp[q];
            float p = o.x * sv.x + o.y * sv.y + o.z * sv.z + o.w * sv.w;
            p += __shfl_xor(p, 1);
            p += __shfl_xor(p, 2);
            p += __shfl_xor(p, 4);
            if (q == 0) scores[wid] = p;
        }
    }
}

// Final SpMM (F=2) + 2-way softmax. One wave per row, one neighbor per lane, float2 loads.
__global__ __launch_bounds__(256) void spmm_out(const int* __restrict__ ell, const int* __restrict__ rowcnt,
        const int* __restrict__ diag, const float* __restrict__ dnorm, const float* __restrict__ Z,
        float* __restrict__ out, int n, int stride)
{
    int wid = (blockIdx.x * 256 + threadIdx.x) >> 6;
    int lane = threadIdx.x & 63;
    if (wid >= n) return;
    int cnt = rowcnt[wid];
    const int* erow = ell + (size_t)wid * stride;
    const float2* Z2 = (const float2*)Z;
    float ax = 0.0f, ay = 0.0f;
    for (int it = lane; it < cnt; it += 64) {
        int c = erow[it];
        float dn = dnorm[c];
        float2 zv = Z2[c];
        ax += dn * zv.x;
        ay += dn * zv.y;
    }
    ax += __shfl_xor(ax, 1);
    ay += __shfl_xor(ay, 1);
    ax += __shfl_xor(ax, 2);
    ay += __shfl_xor(ay, 2);
    ax += __shfl_xor(ax, 4);
    ay += __shfl_xor(ay, 4);
    ax += __shfl_xor(ax, 8);
    ay += __shfl_xor(ay, 8);
    ax += __shfl_xor(ax, 16);
    ay += __shfl_xor(ay, 16);
    ax += __shfl_xor(ax, 32);
    ay += __shfl_xor(ay, 32);
    if (lane == 0) {
        float dr = dnorm[wid];
        float cf = (float)(diag[wid] + 1) * dr;
        float2 zs = Z2[wid];
        ax += cf * zs.x;
        ay += cf * zs.y;
        float v0 = dr * ax;
        float v1 = dr * ay;
        float m = fmaxf(v0, v1);
        float e0 = __expf(v0 - m);
        float e1 = __expf(v1 - m);
        float inv = 1.0f / (e0 + e1);
        float2 r;
        r.x = e0 * inv;
        r.y = e1 * inv;
        ((float2*)out)[wid] = r;
    }
}

// Exact top-K selection replicating jax.lax.top_k SET semantics (value desc,
// lower-index-first ties). Single block, 256 threads. Radix-select the K-th
// key (4x8-bit passes) with wave-privatized histograms and a PARALLEL LDS-scan
// bin select, then tie-exact selection via packed (lt,eq) prefix.
__global__ __launch_bounds__(256) void topk_select(const float* __restrict__ scores, int n, int K,
        int* __restrict__ rank, int* __restrict__ idxlist)
{
    __shared__ unsigned int km_s[8192];
    __shared__ unsigned int part_s[256];
    __shared__ unsigned int histp[4][256];
    __shared__ unsigned int sh_pref;
    __shared__ unsigned int sh_rem;
    int tid = threadIdx.x;
    int wv = tid >> 6;
    int per = n >> 8;       // 32 (N=8192) or 16 (N=4096)
    int base = tid * per;
    for (int e = 0; e < per; ++e) {
        int v = base + e;
        unsigned int u = __float_as_uint(scores[v]);
        unsigned int m;
        if (u & 0x80000000u) m = ~u; else m = u | 0x80000000u;  // monotone asc in float
        km_s[v] = ~m;                                           // asc in km == desc in score
    }
    if (tid == 0) { sh_pref = 0u; sh_rem = (unsigned int)K; }
    __syncthreads();
    for (int bp = 3; bp >= 0; --bp) {
        histp[0][tid] = 0u;
        histp[1][tid] = 0u;
        histp[2][tid] = 0u;
        histp[3][tid] = 0u;
        __syncthreads();
        unsigned int maskhi = 0u;
        if (bp < 3) maskhi = 0xFFFFFFFFu << ((bp + 1) * 8);
        unsigned int pref = sh_pref;
        unsigned int rem = sh_rem;
        for (int e = 0; e < per; ++e) {
            unsigned int km = km_s[base + e];
            if ((km & maskhi) == pref) atomicAdd(&histp[wv][(km >> (bp * 8)) & 255u], 1u);
        }
        __syncthreads();
        // thread tid owns bin tid; inclusive scan of totals across 256 bins
        unsigned int tot = histp[0][tid] + histp[1][tid] + histp[2][tid] + histp[3][tid];
        part_s[tid] = tot;
        __syncthreads();
        for (int offd = 1; offd < 256; offd <<= 1) {
            unsigned int add = 0u;
            if (tid >= offd) add = part_s[tid - offd];
            __syncthreads();
            part_s[tid] += add;
            __syncthreads();
        }
        unsigned int cum = part_s[tid];
        if (tot != 0u && cum >= rem && cum - tot < rem) {  // unique boundary bin
            sh_pref = pref | ((unsigned int)tid << (bp * 8));
            sh_rem = rem - (cum - tot);
        }
        __syncthreads();
    }
    unsigned int T = sh_pref;       // K-th smallest km
    unsigned int need_eq = sh_rem;  // how many km==T to take (lowest node index first)
    // packed counts: high16 = #(km<T), low16 = #(km==T)
    unsigned int run = 0u;
    for (int e = 0; e < per; ++e) {
        unsigned int km = km_s[base + e];
        if (km < T) run += 0x10000u;
        else if (km == T) run += 1u;
    }
    part_s[tid] = run;
    __syncthreads();
    for (int offd = 1; offd < 256; offd <<= 1) {
        unsigned int add = 0u;
        if (tid >= offd) add = part_s[tid - offd];
        __syncthreads();
        part_s[tid] += add;
        __syncthreads();
    }
    unsigned int cur = part_s[tid] - run;   // exclusive prefix for this thread's chunk
    for (int e = 0; e < per; ++e) {
        int v = base + e;
        unsigned int km = km_s[v];
        unsigned int ltb = cur >> 16;
        unsigned int eqb = cur & 0xFFFFu;
        unsigned int eqs = eqb < need_eq ? eqb : need_eq;  // selected equals before v
        int sel = 0;
        if (km < T) { sel = 1; cur += 0x10000u; }
        else if (km == T) { if (eqb < need_eq) sel = 1; cur += 1u; }
        if (sel) {
            int r = (int)(ltb + eqs);       // rank = #selected with index < v
            rank[v] = r;
            idxlist[r] = v;
        } else {
            rank[v] = -1;
        }
    }
}

// Build subgraph ELL for A1p = a[idx1][:,idx1] by filtering the main ELL
// through rank1 (wave-compaction via ballot). One wave per subgraph row.
__global__ __launch_bounds__(256) void build_subell(const int* __restrict__ ellA, const int* __restrict__ rowcntA,
        const int* __restrict__ diagA, const int* __restrict__ idx1, const int* __restrict__ rank1,
        int* __restrict__ ellS, int* __restrict__ rowcntS, int* __restrict__ diagS, float* __restrict__ dnormS,
        int k1, int strideA, int strideS)
{
    int wid = (blockIdx.x * 256 + threadIdx.x) >> 6;
    int lane = threadIdx.x & 63;
    if (wid >= k1) return;
    int r = idx1[wid];
    int cnt = rowcntA[r];
    const int* erow = ellA + (size_t)r * strideA;
    int* srow = ellS + (size_t)wid * strideS;
    int outn = 0;
    for (int t0 = 0; t0 < cnt; t0 += 64) {
        int it = t0 + lane;
        int rk = -1;
        if (it < cnt) rk = rank1[erow[it]];
        unsigned long long b = __ballot(rk >= 0);
        int ofs = __popcll(b & ((1ull << lane) - 1ull));
        if (rk >= 0) srow[outn + ofs] = rk;
        outn += __popcll(b);
    }
    if (lane == 0) {
        int dg = diagA[r];              // A1p diagonal entry = a[r][r]
        rowcntS[wid] = outn;
        diagS[wid] = dg;
        dnormS[wid] = rsqrtf((float)(outn + dg + 1) + 1e-10f);
    }
}

#define CARVE(type, name, bytes) \
    type name = (type)wp; wp += (((size_t)(bytes)) + 255) & ~((size_t)255);

extern "C" void kernel_launch(void* const* d_in, const int* in_sizes, int n_in,
                              void* d_out, int out_size, void* d_ws, size_t ws_size,
                              hipStream_t stream)
{
    const float* x  = (const float*)d_in[0];
    const float* a  = (const float*)d_in[1];
    const float* W1 = (const float*)d_in[2];
    const float* W2 = (const float*)d_in[3];
    const float* W3 = (const float*)d_in[4];
    const float* W4 = (const float*)d_in[5];
    const float* s1 = (const float*)d_in[6];
    const float* s2 = (const float*)d_in[7];
    float* out = (float*)d_out;
    (void)in_sizes; (void)n_in; (void)out_size; (void)ws_size;

    char* wp = (char*)d_ws;
    CARVE(int*,   ellA,  (size_t)NNODES * STRA * sizeof(int));   // 10.5 MB
    CARVE(int*,   cntA,  NNODES * sizeof(int));
    CARVE(int*,   diagA, NNODES * sizeof(int));
    CARVE(float*, dnA,   NNODES * sizeof(float));
    CARVE(float*, Z1,    (size_t)NNODES * FH * sizeof(float));
    CARVE(float*, X1,    (size_t)NNODES * FH * sizeof(float));
    CARVE(float*, sc1,   NNODES * sizeof(float));
    CARVE(int*,   rank1, NNODES * sizeof(int));
    CARVE(int*,   idx1,  NNODES * sizeof(int));
    CARVE(int*,   ellS,  (size_t)KP1 * STRS * sizeof(int));      // 5.2 MB
    CARVE(int*,   cntS,  KP1 * sizeof(int));
    CARVE(int*,   diagS, KP1 * sizeof(int));
    CARVE(float*, dnS,   KP1 * sizeof(float));
    CARVE(float*, Z2,    (size_t)KP1 * FH * sizeof(float));
    CARVE(float*, X2,    (size_t)KP1 * FH * sizeof(float));
    CARVE(float*, sc2,   KP1 * sizeof(float));
    CARVE(int*,   rank2, KP1 * sizeof(int));
    CARVE(int*,   idx2,  KP1 * sizeof(int));
    CARVE(float*, Z3,    (size_t)KP1 * FH * sizeof(float));
    CARVE(float*, X3g,   (size_t)KP1 * FH * sizeof(float));
    CARVE(float*, Z4,    (size_t)NNODES * COUT * sizeof(float));

    // 1) one full pass over a (256 MB) -> sparse structure + degrees
    build_ell<<<NNODES, 256, 0, stream>>>(a, NNODES, STRA, ellA, cntA, diagA, dnA);
    // 2) GCN1: Z1 = x@W1 ; X1 = relu(Anorm@Z1) ; sc1 = X1@s1
    feat_gemm<<<(NNODES * FH) / 256, 256, 0, stream>>>(x, (const int*)0, (const int*)0, W1, Z1, NNODES, FIN, FH);
    spmm_f32<<<NNODES / 4, 256, 0, stream>>>(ellA, cntA, diagA, dnA, Z1,
        (const int*)0, (const int*)0, X1, sc1, s1, NNODES, STRA);
    // 3) pool1 (exact top-k set, index-ascending order — permutation-equivalent)
    topk_select<<<1, 256, 0, stream>>>(sc1, NNODES, KP1, rank1, idx1);
    build_subell<<<KP1 / 4, 256, 0, stream>>>(ellA, cntA, diagA, idx1, rank1, ellS, cntS, diagS, dnS, KP1, STRA, STRS);
    // 4) GCN2 on subgraph: Z2 = X1[idx1]@W2 ; X2 = relu(...) ; sc2 = X2@s2
    feat_gemm<<<(KP1 * FH) / 256, 256, 0, stream>>>(X1, idx1, (const int*)0, W2, Z2, KP1, FH, FH);
    spmm_f32<<<KP1 / 4, 256, 0, stream>>>(ellS, cntS, diagS, dnS, Z2,
        (const int*)0, (const int*)0, X2, sc2, s2, KP1, STRS);
    // 5) pool2 + unpool2 collapse to a row mask (scatter back to the same slots)
    topk_select<<<1, 256, 0, stream>>>(sc2, KP1, KP2, rank2, idx2);
    // 6) GCN3: Z3 = mask(X2)@W3 ; X3g = relu(...) with pool2 mask
    feat_gemm<<<(KP1 * FH) / 256, 256, 0, stream>>>(X2, (const int*)0, rank2, W3, Z3, KP1, FH, FH);
    spmm_f32<<<KP1 / 4, 256, 0, stream>>>(ellS, cntS, diagS, dnS, Z3,
        (const int*)0, rank2, X3g, (float*)0, (const float*)0, KP1, STRS);
    // 7) unpool1 folded into gather: Z4[v] = X3g[rank1[v]] @ W4 (0 if unpooled)
    feat_gemm<<<(NNODES * COUT) / 256, 256, 0, stream>>>(X3g, rank1, (const int*)0, W4, Z4, NNODES, FH, COUT);
    // 8) GCN4 + softmax
    spmm_out<<<NNODES / 4, 256, 0, stream>>>(ellA, cntA, diagA, dnA, Z4, out, NNODES, STRA);
}